// Round 1
// baseline (571.532 us; speedup 1.0000x reference)
//
#include <hip/hip_runtime.h>
#include <cstddef>

// ---------------------------------------------------------------------------
// AttentionSubsample (LeViT-style), B=64, C=256, H=8, KD=16, D=32,
// N=784 (28x28), N_=196 (14x14), stride 2.
//
// Pipeline (all fp32, round-0 correctness baseline):
//   1. bias_kernel   : biasT[h][m][n] = ab[h, idxs[n][m]]   (transposed gather)
//   2. convbn_gemm   : kv = hswish(BN(kv_w @ x))   -> ws  (B,384,784)
//   3. convbn_gemm   : q  = hswish(BN(q_w @ x[::2,::2])) -> ws (B,128,196)
//   4. attn_kernel   : flash-style attention + hswish -> act (B,256,196)
//   5. convbn_gemm   : out = hswish(BN(proj_w @ act)) -> d_out (B,512,196)
// ---------------------------------------------------------------------------

#define SCALE_ATTN 0.25f   // 16^-0.5
#define BN_EPS 1e-5f

__device__ __forceinline__ float hswish(float y) {
    float t = fminf(fmaxf(y + 3.0f, 0.0f), 6.0f);
    return y * t * (1.0f / 6.0f);
}

// ---------------- 1. bias precompute (transposed) ----------------
// biasT[h][m][n], h<8, m<784, n<196
__global__ __launch_bounds__(256)
void bias_kernel(const float* __restrict__ ab, const int* __restrict__ idxs,
                 float* __restrict__ biasT, int n_off)
{
    __shared__ int I[32][33];
    int mx = blockIdx.x * 32, ny = blockIdx.y * 32;
    int tx = threadIdx.x & 31, ty = threadIdx.x >> 5;
#pragma unroll
    for (int i = 0; i < 4; ++i) {
        int nl = ty + i * 8;
        int n = ny + nl, m = mx + tx;
        I[tx][nl] = (n < 196 && m < 784) ? idxs[n * 784 + m] : 0;
    }
    __syncthreads();
#pragma unroll
    for (int i = 0; i < 4; ++i) {
        int ml = ty + i * 8;
        int m = mx + ml, n = ny + tx;
        if (m < 784 && n < 196) {
            int id = I[ml][tx];
#pragma unroll
            for (int h = 0; h < 8; ++h) {
                biasT[((size_t)h * 784 + m) * 196 + n] = ab[h * n_off + id];
            }
        }
    }
}

// ---------------- 2/3/5. conv(1x1) + BN + hardswish as tiled GEMM ----------
// Y[b][o][n] = hswish( (sum_c W[o][c] * X[b][c][src(n)]) * sc[o] + sh[o] )
// O_TILE=64, N_TILE=64, C=256, 256 threads, 4x4 microtile per thread.
template<bool STRIDED>
__global__ __launch_bounds__(256)
void convbn_gemm(const float* __restrict__ X, const float* __restrict__ W,
                 const float* __restrict__ G, const float* __restrict__ Bb,
                 const float* __restrict__ Mm, const float* __restrict__ Vv,
                 float* __restrict__ Y, int O, int N, int xbstride, int HWsrc)
{
    __shared__ float Ws[16][68];
    __shared__ float Xs[16][68];
    const int C = 256;
    int b = blockIdx.z;
    int oBase = blockIdx.y * 64;
    int nBase = blockIdx.x * 64;
    const float* Xb = X + (size_t)b * xbstride;
    int tid = threadIdx.x;
    int to = tid >> 4, tn = tid & 15;
    int wo = tid >> 2, wc4 = (tid & 3) << 2;
    int xc = tid >> 4, xn4 = (tid & 15) << 2;

    float acc[4][4];
#pragma unroll
    for (int i = 0; i < 4; ++i)
#pragma unroll
        for (int j = 0; j < 4; ++j) acc[i][j] = 0.0f;

    for (int c0 = 0; c0 < C; c0 += 16) {
        // stage W tile (64 o x 16 c), transposed into Ws[c][o]
        float4 w4 = *reinterpret_cast<const float4*>(&W[(size_t)(oBase + wo) * C + c0 + wc4]);
        Ws[wc4 + 0][wo] = w4.x;
        Ws[wc4 + 1][wo] = w4.y;
        Ws[wc4 + 2][wo] = w4.z;
        Ws[wc4 + 3][wo] = w4.w;
        // stage X tile (16 c x 64 n)
        int n0 = nBase + xn4;
        if (!STRIDED) {
            float4 x4 = make_float4(0.f, 0.f, 0.f, 0.f);
            if (n0 < N) x4 = *reinterpret_cast<const float4*>(&Xb[(size_t)(c0 + xc) * HWsrc + n0]);
            *reinterpret_cast<float4*>(&Xs[xc][xn4]) = x4;
        } else {
            float vals[4];
#pragma unroll
            for (int j = 0; j < 4; ++j) {
                int nn = n0 + j;
                float vv = 0.0f;
                if (nn < N) {
                    int r = nn / 14, cc = nn - r * 14;      // 14x14 dst grid
                    vv = Xb[(size_t)(c0 + xc) * HWsrc + r * 56 + cc * 2];  // src 28x28, stride 2
                }
                vals[j] = vv;
            }
            Xs[xc][xn4 + 0] = vals[0];
            Xs[xc][xn4 + 1] = vals[1];
            Xs[xc][xn4 + 2] = vals[2];
            Xs[xc][xn4 + 3] = vals[3];
        }
        __syncthreads();
#pragma unroll
        for (int c = 0; c < 16; ++c) {
            float4 a4 = *reinterpret_cast<const float4*>(&Ws[c][to * 4]);
            float4 b4 = *reinterpret_cast<const float4*>(&Xs[c][tn * 4]);
            acc[0][0] += a4.x * b4.x; acc[0][1] += a4.x * b4.y;
            acc[0][2] += a4.x * b4.z; acc[0][3] += a4.x * b4.w;
            acc[1][0] += a4.y * b4.x; acc[1][1] += a4.y * b4.y;
            acc[1][2] += a4.y * b4.z; acc[1][3] += a4.y * b4.w;
            acc[2][0] += a4.z * b4.x; acc[2][1] += a4.z * b4.y;
            acc[2][2] += a4.z * b4.z; acc[2][3] += a4.z * b4.w;
            acc[3][0] += a4.w * b4.x; acc[3][1] += a4.w * b4.y;
            acc[3][2] += a4.w * b4.z; acc[3][3] += a4.w * b4.w;
        }
        __syncthreads();
    }

    int n0 = nBase + tn * 4;
    if (n0 < N) {
#pragma unroll
        for (int i = 0; i < 4; ++i) {
            int o = oBase + to * 4 + i;
            float sc = G[o] * rsqrtf(Vv[o] + BN_EPS);
            float sh = Bb[o] - Mm[o] * sc;
            float4 outv;
            outv.x = hswish(acc[i][0] * sc + sh);
            outv.y = hswish(acc[i][1] * sc + sh);
            outv.z = hswish(acc[i][2] * sc + sh);
            outv.w = hswish(acc[i][3] * sc + sh);
            *reinterpret_cast<float4*>(&Y[((size_t)b * O + o) * N + n0]) = outv;
        }
    }
}

// ---------------- 4. fused attention (flash-style, fp32) ----------------
// One block per (b,h). Thread n (n<196) owns one query row.
// K/V staged transposed in LDS in chunks of 98 m's; online softmax with
// 14-element register sub-chunks.
__global__ __launch_bounds__(256)
void attn_kernel(const float* __restrict__ kv, const float* __restrict__ q,
                 const float* __restrict__ biasT, float* __restrict__ act)
{
    __shared__ float kT[98][20];   // [m][d], d<16, padded row 80B (16B aligned)
    __shared__ float vT[98][36];   // [m][d], d<32, padded row 144B

    int bh = blockIdx.x;
    int b = bh >> 3, h = bh & 7;
    const float* kvb = kv + ((size_t)b * 384 + h * 48) * 784;   // k at d*784, v at (16+d)*784
    const float* qb  = q  + ((size_t)b * 128 + h * 16) * 196;
    const float* bT  = biasT + (size_t)h * (784 * 196);

    int tid = threadIdx.x;
    bool active = tid < 196;
    int n = active ? tid : 0;

    float qr[16];
#pragma unroll
    for (int d = 0; d < 16; ++d) qr[d] = qb[d * 196 + n];

    float accv[32];
#pragma unroll
    for (int d = 0; d < 32; ++d) accv[d] = 0.0f;
    float M = -1e30f, L = 0.0f;

#pragma unroll 1
    for (int m0 = 0; m0 < 784; m0 += 98) {
        // stage K chunk (16 x 98) transposed
        for (int idx = tid; idx < 98 * 16; idx += 256) {
            int d = idx / 98, mm = idx - d * 98;
            kT[mm][d] = kvb[d * 784 + m0 + mm];
        }
        // stage V chunk (32 x 98) transposed
        for (int idx = tid; idx < 98 * 32; idx += 256) {
            int d = idx / 98, mm = idx - d * 98;
            vT[mm][d] = kvb[(16 + d) * 784 + m0 + mm];
        }
        __syncthreads();
        if (active) {
#pragma unroll 1
            for (int sub = 0; sub < 7; ++sub) {
                int mbase = sub * 14;
                float s[14];
                float smax = -1e30f;
#pragma unroll
                for (int t = 0; t < 14; ++t) {
                    int mm = mbase + t;
                    const float4* kp = reinterpret_cast<const float4*>(&kT[mm][0]);
                    float4 k0 = kp[0], k1 = kp[1], k2 = kp[2], k3 = kp[3];
                    float sv = qr[0] * k0.x + qr[1] * k0.y + qr[2] * k0.z + qr[3] * k0.w
                             + qr[4] * k1.x + qr[5] * k1.y + qr[6] * k1.z + qr[7] * k1.w
                             + qr[8] * k2.x + qr[9] * k2.y + qr[10] * k2.z + qr[11] * k2.w
                             + qr[12] * k3.x + qr[13] * k3.y + qr[14] * k3.z + qr[15] * k3.w;
                    sv = sv * SCALE_ATTN + bT[(m0 + mm) * 196 + n];
                    s[t] = sv;
                    smax = fmaxf(smax, sv);
                }
                // branchless online-softmax rescale (corr==1 when no new max)
                float Mn = fmaxf(M, smax);
                float corr = __expf(M - Mn);
                L *= corr;
#pragma unroll
                for (int d = 0; d < 32; ++d) accv[d] *= corr;
                M = Mn;
#pragma unroll
                for (int t = 0; t < 14; ++t) {
                    int mm = mbase + t;
                    float p = __expf(s[t] - M);
                    L += p;
                    const float4* vp = reinterpret_cast<const float4*>(&vT[mm][0]);
#pragma unroll
                    for (int dq = 0; dq < 8; ++dq) {
                        float4 v4 = vp[dq];
                        accv[dq * 4 + 0] += p * v4.x;
                        accv[dq * 4 + 1] += p * v4.y;
                        accv[dq * 4 + 2] += p * v4.z;
                        accv[dq * 4 + 3] += p * v4.w;
                    }
                }
            }
        }
        __syncthreads();
    }

    if (active) {
        float inv = 1.0f / L;
#pragma unroll
        for (int d = 0; d < 32; ++d) {
            float z = accv[d] * inv;
            act[((size_t)b * 256 + h * 32 + d) * 196 + n] = hswish(z);
        }
    }
}

// ---------------------------------------------------------------------------
extern "C" void kernel_launch(void* const* d_in, const int* in_sizes, int n_in,
                              void* d_out, int out_size, void* d_ws, size_t ws_size,
                              hipStream_t stream) {
    const float* x      = (const float*)d_in[0];
    const float* kv_w   = (const float*)d_in[1];
    const float* kv_g   = (const float*)d_in[2];
    const float* kv_b   = (const float*)d_in[3];
    const float* kv_m   = (const float*)d_in[4];
    const float* kv_v   = (const float*)d_in[5];
    const float* q_w    = (const float*)d_in[6];
    const float* q_g    = (const float*)d_in[7];
    const float* q_b    = (const float*)d_in[8];
    const float* q_m    = (const float*)d_in[9];
    const float* q_v    = (const float*)d_in[10];
    const float* proj_w = (const float*)d_in[11];
    const float* proj_g = (const float*)d_in[12];
    const float* proj_b = (const float*)d_in[13];
    const float* proj_m = (const float*)d_in[14];
    const float* proj_v = (const float*)d_in[15];
    const float* ab     = (const float*)d_in[16];
    const int*   idxs   = (const int*)d_in[17];
    float* out = (float*)d_out;

    int n_off = in_sizes[16] / 8;

    // workspace layout (floats)
    const size_t KV_ELEMS   = (size_t)64 * 384 * 784;   // 19,267,584
    const size_t Q_ELEMS    = (size_t)64 * 128 * 196;   //  1,605,632
    const size_t BIAS_ELEMS = (size_t)8 * 784 * 196;    //  1,229,312
    float* kvbuf = (float*)d_ws;
    float* qbuf  = kvbuf + KV_ELEMS;
    float* biasT = qbuf + Q_ELEMS;
    float* actb  = biasT + BIAS_ELEMS;

    // 1. bias gather (transposed)
    {
        dim3 g(25, 7);
        bias_kernel<<<g, 256, 0, stream>>>(ab, idxs, biasT, n_off);
    }
    // 2. kv = hswish(BN(kv_w @ x)) : O=384, N=784
    {
        dim3 g(13, 6, 64);
        convbn_gemm<false><<<g, 256, 0, stream>>>(x, kv_w, kv_g, kv_b, kv_m, kv_v,
                                                  kvbuf, 384, 784, 256 * 784, 784);
    }
    // 3. q = hswish(BN(q_w @ x[::2,::2])) : O=128, N=196
    {
        dim3 g(4, 2, 64);
        convbn_gemm<true><<<g, 256, 0, stream>>>(x, q_w, q_g, q_b, q_m, q_v,
                                                 qbuf, 128, 196, 256 * 784, 784);
    }
    // 4. attention + hardswish -> act
    {
        attn_kernel<<<512, 256, 0, stream>>>(kvbuf, qbuf, biasT, actb);
    }
    // 5. out = hswish(BN(proj_w @ act)) : O=512, N=196
    {
        dim3 g(4, 8, 64);
        convbn_gemm<false><<<g, 256, 0, stream>>>(actb, proj_w, proj_g, proj_b, proj_m, proj_v,
                                                  out, 512, 196, 256 * 196, 196);
    }
}

// Round 2
// 518.394 us; speedup vs baseline: 1.1025x; 1.1025x over previous
//
#include <hip/hip_runtime.h>
#include <cstddef>

// ---------------------------------------------------------------------------
// AttentionSubsample (LeViT-style), B=64, C=256, H=8, KD=16, D=32,
// N=784 (28x28), N_=196 (14x14), stride 2.
//
// Round 1: conv+BN+hardswish GEMMs moved to MFMA (bf16 hi/lo split for
// fp32-level accuracy). Attention unchanged (MFMA rewrite next round).
//   1. bias_kernel   : biasT[h][m][n] = ab[h, idxs[n][m]]
//   2. convbn_mfma   : kv  -> ws (B,384,784) fp32
//   3. convbn_mfma   : q   -> ws (B,128,196) fp32   (strided x view)
//   4. attn_kernel   : flash-style attention + hswish -> act (B,256,196)
//   5. convbn_mfma   : out -> d_out (B,512,196) fp32
// ---------------------------------------------------------------------------

#define SCALE_ATTN 0.25f   // 16^-0.5
#define BN_EPS 1e-5f

typedef short s8v  __attribute__((ext_vector_type(8)));
typedef short s4v  __attribute__((ext_vector_type(4)));
typedef float f4v  __attribute__((ext_vector_type(4)));

__device__ __forceinline__ float hswish(float y) {
    float t = fminf(fmaxf(y + 3.0f, 0.0f), 6.0f);
    return y * t * (1.0f / 6.0f);
}

// round-to-nearest-even fp32 -> bf16 bits
__device__ __forceinline__ unsigned short bf16_rn(float f) {
    unsigned u = __float_as_uint(f);
    unsigned r = (u + 0x7FFFu + ((u >> 16) & 1u)) >> 16;
    return (unsigned short)r;
}
__device__ __forceinline__ float bf16_to_f(unsigned short h) {
    return __uint_as_float(((unsigned)h) << 16);
}

// ---------------- 1. bias precompute (transposed) ----------------
// biasT[h][m][n], h<8, m<784, n<196
__global__ __launch_bounds__(256)
void bias_kernel(const float* __restrict__ ab, const int* __restrict__ idxs,
                 float* __restrict__ biasT, int n_off)
{
    __shared__ int I[32][33];
    int mx = blockIdx.x * 32, ny = blockIdx.y * 32;
    int tx = threadIdx.x & 31, ty = threadIdx.x >> 5;
#pragma unroll
    for (int i = 0; i < 4; ++i) {
        int nl = ty + i * 8;
        int n = ny + nl, m = mx + tx;
        I[tx][nl] = (n < 196 && m < 784) ? idxs[n * 784 + m] : 0;
    }
    __syncthreads();
#pragma unroll
    for (int i = 0; i < 4; ++i) {
        int ml = ty + i * 8;
        int m = mx + ml, n = ny + tx;
        if (m < 784 && n < 196) {
            int id = I[ml][tx];
#pragma unroll
            for (int h = 0; h < 8; ++h) {
                biasT[((size_t)h * 784 + m) * 196 + n] = ab[h * n_off + id];
            }
        }
    }
}

// ---------------- 2/3/5. conv(1x1)+BN+hswish via bf16 hi/lo MFMA -----------
// Y[b][o][n] = hswish( (sum_c W[o][c] * X[b][c][src(n)]) * sc[o] + sh[o] )
// Block tile 64(o) x 64(n), K=256 in 4 chunks of 64. 4 waves, 32x32 each.
// Split-bf16: x = hi + lo; acc += Ah*Bh + Ah*Bl + Al*Bh (lo*lo dropped).
template<bool STRIDED>
__global__ __launch_bounds__(256)
void convbn_mfma(const float* __restrict__ X, const float* __restrict__ W,
                 const float* __restrict__ G, const float* __restrict__ Bb,
                 const float* __restrict__ Mm, const float* __restrict__ Vv,
                 float* __restrict__ Y, int O, int N, int xbstride, int HWsrc)
{
    __shared__ short Ah[64][72];   // W tile  [o_local][c_local], +8 pad
    __shared__ short Al[64][72];
    __shared__ short Bh[64][72];   // X tile transposed [n_local][c_local]
    __shared__ short Bl[64][72];
    __shared__ float scs[64], shs[64];

    const int C = 256;
    int b = blockIdx.z;
    int oBase = blockIdx.y * 64;
    int nBase = blockIdx.x * 64;
    const float* Xb = X + (size_t)b * xbstride;
    int tid = threadIdx.x;
    int w = tid >> 6, l = tid & 63;
    int wm = w >> 1, wn = w & 1;

    if (tid < 64) {
        int o = oBase + tid;
        float sc = G[o] * rsqrtf(Vv[o] + BN_EPS);
        scs[tid] = sc;
        shs[tid] = Bb[o] - Mm[o] * sc;
    }

    f4v acc[2][2];
#pragma unroll
    for (int i = 0; i < 2; ++i)
#pragma unroll
        for (int j = 0; j < 2; ++j) acc[i][j] = (f4v)0.0f;

    // staging thread mapping: sr = row 0..15 (stepped by 16), sc4 = col quad
    int sr  = tid >> 4;
    int sc4 = (tid & 15) * 4;
    int fr = l & 15, fk = (l >> 4) * 8;   // fragment row / k-offset

    for (int c0 = 0; c0 < C; c0 += 64) {
        __syncthreads();
        // ---- stage A (W 64x64) ----
#pragma unroll
        for (int jo = 0; jo < 4; ++jo) {
            int o = sr + jo * 16;
            float4 wv = *reinterpret_cast<const float4*>(
                &W[(size_t)(oBase + o) * C + c0 + sc4]);
            s4v hv, lv;
            {
                unsigned short h;
                h = bf16_rn(wv.x); hv[0] = (short)h; lv[0] = (short)bf16_rn(wv.x - bf16_to_f(h));
                h = bf16_rn(wv.y); hv[1] = (short)h; lv[1] = (short)bf16_rn(wv.y - bf16_to_f(h));
                h = bf16_rn(wv.z); hv[2] = (short)h; lv[2] = (short)bf16_rn(wv.z - bf16_to_f(h));
                h = bf16_rn(wv.w); hv[3] = (short)h; lv[3] = (short)bf16_rn(wv.w - bf16_to_f(h));
            }
            *reinterpret_cast<s4v*>(&Ah[o][sc4]) = hv;
            *reinterpret_cast<s4v*>(&Al[o][sc4]) = lv;
        }
        // ---- stage B (X 64c x 64n, transposed into [n][c]) ----
#pragma unroll
        for (int jc = 0; jc < 4; ++jc) {
            int c = sr + jc * 16;           // chunk-local c
            float vals[4];
            if (!STRIDED) {
                if (nBase + sc4 + 3 < N) {
                    float4 xv = *reinterpret_cast<const float4*>(
                        &Xb[(size_t)(c0 + c) * HWsrc + nBase + sc4]);
                    vals[0] = xv.x; vals[1] = xv.y; vals[2] = xv.z; vals[3] = xv.w;
                } else {
#pragma unroll
                    for (int e = 0; e < 4; ++e) {
                        int nn = nBase + sc4 + e;
                        vals[e] = (nn < N) ? Xb[(size_t)(c0 + c) * HWsrc + nn] : 0.0f;
                    }
                }
            } else {
#pragma unroll
                for (int e = 0; e < 4; ++e) {
                    int nn = nBase + sc4 + e;
                    float vv = 0.0f;
                    if (nn < N) {
                        int r = nn / 14, cc = nn - r * 14;          // dst 14x14
                        vv = Xb[(size_t)(c0 + c) * HWsrc + r * 56 + cc * 2];  // src 28x28
                    }
                    vals[e] = vv;
                }
            }
#pragma unroll
            for (int e = 0; e < 4; ++e) {
                unsigned short h = bf16_rn(vals[e]);
                Bh[sc4 + e][c] = (short)h;
                Bl[sc4 + e][c] = (short)bf16_rn(vals[e] - bf16_to_f(h));
            }
        }
        __syncthreads();
        // ---- MFMA: 2 k-substeps of 32 ----
#pragma unroll
        for (int ks = 0; ks < 2; ++ks) {
            s8v aH[2], aL[2], bH[2], bL[2];
#pragma unroll
            for (int mf = 0; mf < 2; ++mf) {
                aH[mf] = *reinterpret_cast<const s8v*>(&Ah[wm * 32 + mf * 16 + fr][ks * 32 + fk]);
                aL[mf] = *reinterpret_cast<const s8v*>(&Al[wm * 32 + mf * 16 + fr][ks * 32 + fk]);
            }
#pragma unroll
            for (int nf = 0; nf < 2; ++nf) {
                bH[nf] = *reinterpret_cast<const s8v*>(&Bh[wn * 32 + nf * 16 + fr][ks * 32 + fk]);
                bL[nf] = *reinterpret_cast<const s8v*>(&Bl[wn * 32 + nf * 16 + fr][ks * 32 + fk]);
            }
#pragma unroll
            for (int mf = 0; mf < 2; ++mf)
#pragma unroll
                for (int nf = 0; nf < 2; ++nf) {
                    acc[mf][nf] = __builtin_amdgcn_mfma_f32_16x16x32_bf16(aH[mf], bH[nf], acc[mf][nf], 0, 0, 0);
                    acc[mf][nf] = __builtin_amdgcn_mfma_f32_16x16x32_bf16(aH[mf], bL[nf], acc[mf][nf], 0, 0, 0);
                    acc[mf][nf] = __builtin_amdgcn_mfma_f32_16x16x32_bf16(aL[mf], bH[nf], acc[mf][nf], 0, 0, 0);
                }
        }
    }

    // ---- epilogue: BN + hswish, fp32 store ----
    int lr = l >> 4;   // acc row group
#pragma unroll
    for (int mf = 0; mf < 2; ++mf)
#pragma unroll
        for (int nf = 0; nf < 2; ++nf) {
            int n = nBase + wn * 32 + nf * 16 + fr;
            if (n < N) {
#pragma unroll
                for (int i = 0; i < 4; ++i) {
                    int ol = wm * 32 + mf * 16 + lr * 4 + i;
                    float v = acc[mf][nf][i] * scs[ol] + shs[ol];
                    Y[((size_t)b * O + oBase + ol) * N + n] = hswish(v);
                }
            }
        }
}

// ---------------- 4. fused attention (flash-style, fp32) ----------------
// One block per (b,h). Thread n (n<196) owns one query row.
__global__ __launch_bounds__(256)
void attn_kernel(const float* __restrict__ kv, const float* __restrict__ q,
                 const float* __restrict__ biasT, float* __restrict__ act)
{
    __shared__ float kT[98][20];   // [m][d], d<16
    __shared__ float vT[98][36];   // [m][d], d<32

    int bh = blockIdx.x;
    int b = bh >> 3, h = bh & 7;
    const float* kvb = kv + ((size_t)b * 384 + h * 48) * 784;
    const float* qb  = q  + ((size_t)b * 128 + h * 16) * 196;
    const float* bT  = biasT + (size_t)h * (784 * 196);

    int tid = threadIdx.x;
    bool active = tid < 196;
    int n = active ? tid : 0;

    float qr[16];
#pragma unroll
    for (int d = 0; d < 16; ++d) qr[d] = qb[d * 196 + n];

    float accv[32];
#pragma unroll
    for (int d = 0; d < 32; ++d) accv[d] = 0.0f;
    float M = -1e30f, L = 0.0f;

#pragma unroll 1
    for (int m0 = 0; m0 < 784; m0 += 98) {
        for (int idx = tid; idx < 98 * 16; idx += 256) {
            int d = idx / 98, mm = idx - d * 98;
            kT[mm][d] = kvb[d * 784 + m0 + mm];
        }
        for (int idx = tid; idx < 98 * 32; idx += 256) {
            int d = idx / 98, mm = idx - d * 98;
            vT[mm][d] = kvb[(16 + d) * 784 + m0 + mm];
        }
        __syncthreads();
        if (active) {
#pragma unroll 1
            for (int sub = 0; sub < 7; ++sub) {
                int mbase = sub * 14;
                float s[14];
                float smax = -1e30f;
#pragma unroll
                for (int t = 0; t < 14; ++t) {
                    int mm = mbase + t;
                    const float4* kp = reinterpret_cast<const float4*>(&kT[mm][0]);
                    float4 k0 = kp[0], k1 = kp[1], k2 = kp[2], k3 = kp[3];
                    float sv = qr[0] * k0.x + qr[1] * k0.y + qr[2] * k0.z + qr[3] * k0.w
                             + qr[4] * k1.x + qr[5] * k1.y + qr[6] * k1.z + qr[7] * k1.w
                             + qr[8] * k2.x + qr[9] * k2.y + qr[10] * k2.z + qr[11] * k2.w
                             + qr[12] * k3.x + qr[13] * k3.y + qr[14] * k3.z + qr[15] * k3.w;
                    sv = sv * SCALE_ATTN + bT[(m0 + mm) * 196 + n];
                    s[t] = sv;
                    smax = fmaxf(smax, sv);
                }
                float Mn = fmaxf(M, smax);
                float corr = __expf(M - Mn);
                L *= corr;
#pragma unroll
                for (int d = 0; d < 32; ++d) accv[d] *= corr;
                M = Mn;
#pragma unroll
                for (int t = 0; t < 14; ++t) {
                    int mm = mbase + t;
                    float p = __expf(s[t] - M);
                    L += p;
                    const float4* vp = reinterpret_cast<const float4*>(&vT[mm][0]);
#pragma unroll
                    for (int dq = 0; dq < 8; ++dq) {
                        float4 v4 = vp[dq];
                        accv[dq * 4 + 0] += p * v4.x;
                        accv[dq * 4 + 1] += p * v4.y;
                        accv[dq * 4 + 2] += p * v4.z;
                        accv[dq * 4 + 3] += p * v4.w;
                    }
                }
            }
        }
        __syncthreads();
    }

    if (active) {
        float inv = 1.0f / L;
#pragma unroll
        for (int d = 0; d < 32; ++d) {
            float z = accv[d] * inv;
            act[((size_t)b * 256 + h * 32 + d) * 196 + n] = hswish(z);
        }
    }
}

// ---------------------------------------------------------------------------
extern "C" void kernel_launch(void* const* d_in, const int* in_sizes, int n_in,
                              void* d_out, int out_size, void* d_ws, size_t ws_size,
                              hipStream_t stream) {
    const float* x      = (const float*)d_in[0];
    const float* kv_w   = (const float*)d_in[1];
    const float* kv_g   = (const float*)d_in[2];
    const float* kv_b   = (const float*)d_in[3];
    const float* kv_m   = (const float*)d_in[4];
    const float* kv_v   = (const float*)d_in[5];
    const float* q_w    = (const float*)d_in[6];
    const float* q_g    = (const float*)d_in[7];
    const float* q_b    = (const float*)d_in[8];
    const float* q_m    = (const float*)d_in[9];
    const float* q_v    = (const float*)d_in[10];
    const float* proj_w = (const float*)d_in[11];
    const float* proj_g = (const float*)d_in[12];
    const float* proj_b = (const float*)d_in[13];
    const float* proj_m = (const float*)d_in[14];
    const float* proj_v = (const float*)d_in[15];
    const float* ab     = (const float*)d_in[16];
    const int*   idxs   = (const int*)d_in[17];
    float* out = (float*)d_out;

    int n_off = in_sizes[16] / 8;

    // workspace layout (floats)
    const size_t KV_ELEMS   = (size_t)64 * 384 * 784;
    const size_t Q_ELEMS    = (size_t)64 * 128 * 196;
    const size_t BIAS_ELEMS = (size_t)8 * 784 * 196;
    float* kvbuf = (float*)d_ws;
    float* qbuf  = kvbuf + KV_ELEMS;
    float* biasT = qbuf + Q_ELEMS;
    float* actb  = biasT + BIAS_ELEMS;

    // 1. bias gather (transposed)
    {
        dim3 g(25, 7);
        bias_kernel<<<g, 256, 0, stream>>>(ab, idxs, biasT, n_off);
    }
    // 2. kv : O=384, N=784
    {
        dim3 g(13, 6, 64);
        convbn_mfma<false><<<g, 256, 0, stream>>>(x, kv_w, kv_g, kv_b, kv_m, kv_v,
                                                  kvbuf, 384, 784, 256 * 784, 784);
    }
    // 3. q : O=128, N=196 (strided x)
    {
        dim3 g(4, 2, 64);
        convbn_mfma<true><<<g, 256, 0, stream>>>(x, q_w, q_g, q_b, q_m, q_v,
                                                 qbuf, 128, 196, 256 * 784, 784);
    }
    // 4. attention + hardswish -> act
    {
        attn_kernel<<<512, 256, 0, stream>>>(kvbuf, qbuf, biasT, actb);
    }
    // 5. proj : O=512, N=196
    {
        dim3 g(4, 8, 64);
        convbn_mfma<false><<<g, 256, 0, stream>>>(actb, proj_w, proj_g, proj_b, proj_m, proj_v,
                                                  out, 512, 196, 256 * 196, 196);
    }
}

// Round 3
// 396.925 us; speedup vs baseline: 1.4399x; 1.3060x over previous
//
#include <hip/hip_runtime.h>
#include <cstddef>

// ---------------------------------------------------------------------------
// AttentionSubsample (LeViT-style), B=64, C=256, H=8, KD=16, D=32,
// N=784 (28x28), N_=196 (14x14), stride 2.
//
// Round 2: attention rewritten on MFMA (flash-style, per-(b,h) block).
//   1. bias_kernel   : biasB[h][m][208] = bf16(ab[h, idxs[n][m]]) (padded)
//   2. convbn_mfma   : kv  -> ws (B,384,784) fp32
//   3. convbn_mfma   : q   -> ws (B,128,196) fp32   (strided x view)
//   4. attn_mfma     : MFMA flash attention + hswish -> act (B,256,196)
//   5. convbn_mfma   : out -> d_out (B,512,196) fp32
// ---------------------------------------------------------------------------

#define SCALE_ATTN 0.25f   // 16^-0.5
#define BN_EPS 1e-5f

typedef short s8v  __attribute__((ext_vector_type(8)));
typedef short s4v  __attribute__((ext_vector_type(4)));
typedef float f4v  __attribute__((ext_vector_type(4)));

__device__ __forceinline__ float hswish(float y) {
    float t = fminf(fmaxf(y + 3.0f, 0.0f), 6.0f);
    return y * t * (1.0f / 6.0f);
}

// round-to-nearest-even fp32 -> bf16 bits
__device__ __forceinline__ unsigned short bf16_rn(float f) {
    unsigned u = __float_as_uint(f);
    unsigned r = (u + 0x7FFFu + ((u >> 16) & 1u)) >> 16;
    return (unsigned short)r;
}
__device__ __forceinline__ float bf16_to_f(unsigned short h) {
    return __uint_as_float(((unsigned)h) << 16);
}

// ---------------- 1. bias precompute (bf16, transposed, padded) ----------
// biasB[h][m][n], h<8, m<784, n<208 (196..207 zero)
__global__ __launch_bounds__(256)
void bias_kernel(const float* __restrict__ ab, const int* __restrict__ idxs,
                 unsigned short* __restrict__ biasB, int n_off)
{
    __shared__ int I[32][33];
    int mx = blockIdx.x * 32, ny = blockIdx.y * 32;
    int tx = threadIdx.x & 31, ty = threadIdx.x >> 5;
#pragma unroll
    for (int i = 0; i < 4; ++i) {
        int nl = ty + i * 8;
        int n = ny + nl, m = mx + tx;
        I[tx][nl] = (n < 196 && m < 784) ? idxs[n * 784 + m] : 0;
    }
    __syncthreads();
#pragma unroll
    for (int i = 0; i < 4; ++i) {
        int ml = ty + i * 8;
        int m = mx + ml, n = ny + tx;
        if (m < 784 && n < 208) {
            float v = 0.0f;
            if (n < 196) {
                int id = I[ml][tx];
#pragma unroll
                for (int h = 0; h < 8; ++h) {
                    biasB[((size_t)h * 784 + m) * 208 + n] = bf16_rn(ab[h * n_off + id]);
                }
            } else {
#pragma unroll
                for (int h = 0; h < 8; ++h) {
                    biasB[((size_t)h * 784 + m) * 208 + n] = 0;
                }
            }
            (void)v;
        }
    }
}

// ---------------- 2/3/5. conv(1x1)+BN+hswish via bf16 hi/lo MFMA -----------
template<bool STRIDED>
__global__ __launch_bounds__(256)
void convbn_mfma(const float* __restrict__ X, const float* __restrict__ W,
                 const float* __restrict__ G, const float* __restrict__ Bb,
                 const float* __restrict__ Mm, const float* __restrict__ Vv,
                 float* __restrict__ Y, int O, int N, int xbstride, int HWsrc)
{
    __shared__ short Ah[64][72];   // W tile  [o_local][c_local], +8 pad
    __shared__ short Al[64][72];
    __shared__ short Bh[64][72];   // X tile transposed [n_local][c_local]
    __shared__ short Bl[64][72];
    __shared__ float scs[64], shs[64];

    const int C = 256;
    int b = blockIdx.z;
    int oBase = blockIdx.y * 64;
    int nBase = blockIdx.x * 64;
    const float* Xb = X + (size_t)b * xbstride;
    int tid = threadIdx.x;
    int w = tid >> 6, l = tid & 63;
    int wm = w >> 1, wn = w & 1;

    if (tid < 64) {
        int o = oBase + tid;
        float sc = G[o] * rsqrtf(Vv[o] + BN_EPS);
        scs[tid] = sc;
        shs[tid] = Bb[o] - Mm[o] * sc;
    }

    f4v acc[2][2];
#pragma unroll
    for (int i = 0; i < 2; ++i)
#pragma unroll
        for (int j = 0; j < 2; ++j) acc[i][j] = (f4v)0.0f;

    int sr  = tid >> 4;
    int sc4 = (tid & 15) * 4;
    int fr = l & 15, fk = (l >> 4) * 8;

    for (int c0 = 0; c0 < C; c0 += 64) {
        __syncthreads();
#pragma unroll
        for (int jo = 0; jo < 4; ++jo) {
            int o = sr + jo * 16;
            float4 wv = *reinterpret_cast<const float4*>(
                &W[(size_t)(oBase + o) * C + c0 + sc4]);
            s4v hv, lv;
            {
                unsigned short h;
                h = bf16_rn(wv.x); hv[0] = (short)h; lv[0] = (short)bf16_rn(wv.x - bf16_to_f(h));
                h = bf16_rn(wv.y); hv[1] = (short)h; lv[1] = (short)bf16_rn(wv.y - bf16_to_f(h));
                h = bf16_rn(wv.z); hv[2] = (short)h; lv[2] = (short)bf16_rn(wv.z - bf16_to_f(h));
                h = bf16_rn(wv.w); hv[3] = (short)h; lv[3] = (short)bf16_rn(wv.w - bf16_to_f(h));
            }
            *reinterpret_cast<s4v*>(&Ah[o][sc4]) = hv;
            *reinterpret_cast<s4v*>(&Al[o][sc4]) = lv;
        }
#pragma unroll
        for (int jc = 0; jc < 4; ++jc) {
            int c = sr + jc * 16;
            float vals[4];
            if (!STRIDED) {
                if (nBase + sc4 + 3 < N) {
                    float4 xv = *reinterpret_cast<const float4*>(
                        &Xb[(size_t)(c0 + c) * HWsrc + nBase + sc4]);
                    vals[0] = xv.x; vals[1] = xv.y; vals[2] = xv.z; vals[3] = xv.w;
                } else {
#pragma unroll
                    for (int e = 0; e < 4; ++e) {
                        int nn = nBase + sc4 + e;
                        vals[e] = (nn < N) ? Xb[(size_t)(c0 + c) * HWsrc + nn] : 0.0f;
                    }
                }
            } else {
#pragma unroll
                for (int e = 0; e < 4; ++e) {
                    int nn = nBase + sc4 + e;
                    float vv = 0.0f;
                    if (nn < N) {
                        int r = nn / 14, cc = nn - r * 14;
                        vv = Xb[(size_t)(c0 + c) * HWsrc + r * 56 + cc * 2];
                    }
                    vals[e] = vv;
                }
            }
#pragma unroll
            for (int e = 0; e < 4; ++e) {
                unsigned short h = bf16_rn(vals[e]);
                Bh[sc4 + e][c] = (short)h;
                Bl[sc4 + e][c] = (short)bf16_rn(vals[e] - bf16_to_f(h));
            }
        }
        __syncthreads();
#pragma unroll
        for (int ks = 0; ks < 2; ++ks) {
            s8v aH[2], aL[2], bH[2], bL[2];
#pragma unroll
            for (int mf = 0; mf < 2; ++mf) {
                aH[mf] = *reinterpret_cast<const s8v*>(&Ah[wm * 32 + mf * 16 + fr][ks * 32 + fk]);
                aL[mf] = *reinterpret_cast<const s8v*>(&Al[wm * 32 + mf * 16 + fr][ks * 32 + fk]);
            }
#pragma unroll
            for (int nf = 0; nf < 2; ++nf) {
                bH[nf] = *reinterpret_cast<const s8v*>(&Bh[wn * 32 + nf * 16 + fr][ks * 32 + fk]);
                bL[nf] = *reinterpret_cast<const s8v*>(&Bl[wn * 32 + nf * 16 + fr][ks * 32 + fk]);
            }
#pragma unroll
            for (int mf = 0; mf < 2; ++mf)
#pragma unroll
                for (int nf = 0; nf < 2; ++nf) {
                    acc[mf][nf] = __builtin_amdgcn_mfma_f32_16x16x32_bf16(aH[mf], bH[nf], acc[mf][nf], 0, 0, 0);
                    acc[mf][nf] = __builtin_amdgcn_mfma_f32_16x16x32_bf16(aH[mf], bL[nf], acc[mf][nf], 0, 0, 0);
                    acc[mf][nf] = __builtin_amdgcn_mfma_f32_16x16x32_bf16(aL[mf], bH[nf], acc[mf][nf], 0, 0, 0);
                }
        }
    }

    int lr = l >> 4;
#pragma unroll
    for (int mf = 0; mf < 2; ++mf)
#pragma unroll
        for (int nf = 0; nf < 2; ++nf) {
            int n = nBase + wn * 32 + nf * 16 + fr;
            if (n < N) {
#pragma unroll
                for (int i = 0; i < 4; ++i) {
                    int ol = wm * 32 + mf * 16 + lr * 4 + i;
                    float v = acc[mf][nf][i] * scs[ol] + shs[ol];
                    Y[((size_t)b * O + oBase + ol) * N + n] = hswish(v);
                }
            }
        }
}

// ---------------- 4. MFMA flash attention ----------------
// One block per (b,h), 4 waves. m-chunks of 64 staged in LDS; each wave
// owns n-tiles {w, w+4, w+8, (w==0: 12)} of 16 query columns.
// QK^T: A=K^T (split hi/lo), B=Q^T (split hi/lo), K dim zero-padded 16->32.
// Softmax in C-layout regs (n=lane&15), defer-max thr=8, P->bf16 via LDS.
// PV: A=V, B=P. Output C[d][n] stored with hswish.
__global__ __launch_bounds__(256)
void attn_mfma(const float* __restrict__ kv, const float* __restrict__ q,
               const unsigned short* __restrict__ biasB, float* __restrict__ act)
{
    __shared__ short Kh[64][24];            // K^T chunk hi [m][d], 48B rows
    __shared__ short Kl[64][24];            // K^T chunk lo
    __shared__ short Vs[32][72];            // V chunk [d][m], 144B rows
    __shared__ unsigned short Bia[64][208]; // bias chunk [m][n]
    __shared__ short Pl[4][16][72];         // per-wave P [n][m], 144B rows

    int bh = blockIdx.x;
    int b = bh >> 3, h = bh & 7;
    const float* kvb = kv + ((size_t)b * 384 + h * 48) * 784;
    const float* qb  = q  + ((size_t)b * 128 + h * 16) * 196;
    const unsigned short* bB = biasB + (size_t)h * 784 * 208;

    int tid = threadIdx.x;
    int w = tid >> 6, l = tid & 63;
    int g = l >> 4, fr = l & 15;

    // ---- load Q fragments (hi/lo) for this wave's tiles ----
    s8v qh[4], ql[4];
#pragma unroll
    for (int i = 0; i < 4; ++i) { qh[i] = (s8v)0; ql[i] = (s8v)0; }
#pragma unroll
    for (int i = 0; i < 4; ++i) {
        int tile = i * 4 + w;
        if (tile < 13 && g < 2) {
            int n = tile * 16 + fr;
            if (n < 196) {
#pragma unroll
                for (int j = 0; j < 8; ++j) {
                    int d = g * 8 + j;
                    float qv = qb[(size_t)d * 196 + n];
                    unsigned short hh = bf16_rn(qv);
                    qh[i][j] = (short)hh;
                    ql[i][j] = (short)bf16_rn(qv - bf16_to_f(hh));
                }
            }
        }
    }

    f4v Oa[4][2];
    float M[4], L[4];
#pragma unroll
    for (int i = 0; i < 4; ++i) {
        Oa[i][0] = (f4v)0.0f; Oa[i][1] = (f4v)0.0f;
        M[i] = -1e30f; L[i] = 0.0f;
    }

#pragma unroll 1
    for (int ch = 0; ch < 13; ++ch) {
        int m0 = ch * 64;
        int mlim = (784 - m0 < 64) ? (784 - m0) : 64;   // 64 or 16
        __syncthreads();
        // ---- stage K^T chunk (hi/lo) ----
        {
            int d = tid >> 4, m4 = tid & 15;
            float4 kvv = make_float4(0.f, 0.f, 0.f, 0.f);
            if (m4 * 4 < mlim)
                kvv = *reinterpret_cast<const float4*>(&kvb[(size_t)d * 784 + m0 + m4 * 4]);
            float e0[4] = {kvv.x, kvv.y, kvv.z, kvv.w};
#pragma unroll
            for (int e = 0; e < 4; ++e) {
                unsigned short hh = bf16_rn(e0[e]);
                Kh[m4 * 4 + e][d] = (short)hh;
                Kl[m4 * 4 + e][d] = (short)bf16_rn(e0[e] - bf16_to_f(hh));
            }
        }
        // ---- stage V chunk ----
        {
            int d = tid >> 3, m8 = (tid & 7) * 8;
            float4 a = make_float4(0.f, 0.f, 0.f, 0.f), c4 = a;
            if (m8 < mlim) {
                a  = *reinterpret_cast<const float4*>(&kvb[(size_t)(16 + d) * 784 + m0 + m8]);
                c4 = *reinterpret_cast<const float4*>(&kvb[(size_t)(16 + d) * 784 + m0 + m8 + 4]);
            }
            s4v v0, v1;
            v0[0] = (short)bf16_rn(a.x);  v0[1] = (short)bf16_rn(a.y);
            v0[2] = (short)bf16_rn(a.z);  v0[3] = (short)bf16_rn(a.w);
            v1[0] = (short)bf16_rn(c4.x); v1[1] = (short)bf16_rn(c4.y);
            v1[2] = (short)bf16_rn(c4.z); v1[3] = (short)bf16_rn(c4.w);
            *reinterpret_cast<s4v*>(&Vs[d][m8])     = v0;
            *reinterpret_cast<s4v*>(&Vs[d][m8 + 4]) = v1;
        }
        // ---- stage bias chunk (bf16, coalesced int4) ----
        {
            for (int it = tid; it < 64 * 26; it += 256) {
                int r = it / 26, cseg = it - r * 26;
                int4 vz = make_int4(0, 0, 0, 0);
                if (r < mlim)
                    vz = *reinterpret_cast<const int4*>(&bB[(size_t)(m0 + r) * 208 + cseg * 8]);
                *reinterpret_cast<int4*>(&Bia[r][cseg * 8]) = vz;
            }
        }
        __syncthreads();

        // ---- compute ----
#pragma unroll
        for (int i = 0; i < 4; ++i) {
            int tile = i * 4 + w;
            if (tile >= 13) continue;
            int n = tile * 16 + fr;

            // QK^T: 4 m-subtiles
            float s[4][4];
#pragma unroll
            for (int sub = 0; sub < 4; ++sub) {
                s8v ah = (s8v)0, al = (s8v)0;
                if (g < 2) {
                    ah = *reinterpret_cast<const s8v*>(&Kh[sub * 16 + fr][g * 8]);
                    al = *reinterpret_cast<const s8v*>(&Kl[sub * 16 + fr][g * 8]);
                }
                f4v acc = (f4v)0.0f;
                acc = __builtin_amdgcn_mfma_f32_16x16x32_bf16(ah, qh[i], acc, 0, 0, 0);
                acc = __builtin_amdgcn_mfma_f32_16x16x32_bf16(ah, ql[i], acc, 0, 0, 0);
                acc = __builtin_amdgcn_mfma_f32_16x16x32_bf16(al, qh[i], acc, 0, 0, 0);
#pragma unroll
                for (int e = 0; e < 4; ++e) {
                    int mm = sub * 16 + g * 4 + e;
                    s[sub][e] = acc[e] * SCALE_ATTN + bf16_to_f(Bia[mm][n]);
                }
            }
            // chunk max (over this lane's 16 m, then across g groups)
            float mx = s[0][0];
#pragma unroll
            for (int sub = 0; sub < 4; ++sub)
#pragma unroll
                for (int e = 0; e < 4; ++e) mx = fmaxf(mx, s[sub][e]);
            mx = fmaxf(mx, __shfl_xor(mx, 16));
            mx = fmaxf(mx, __shfl_xor(mx, 32));
            // defer-max rescale
            if (__any(mx > M[i] + 8.0f)) {
                float Mn = fmaxf(M[i], mx);
                float corr = __expf(M[i] - Mn);
                L[i] *= corr;
#pragma unroll
                for (int e = 0; e < 4; ++e) { Oa[i][0][e] *= corr; Oa[i][1][e] *= corr; }
                M[i] = Mn;
            }
            // P = exp(s - M), masked; sum into L; pack bf16 into Pl
            float Ls = 0.0f;
#pragma unroll
            for (int sub = 0; sub < 4; ++sub) {
                float p[4];
#pragma unroll
                for (int e = 0; e < 4; ++e) {
                    int mm = sub * 16 + g * 4 + e;
                    float pv = __expf(s[sub][e] - M[i]);
                    p[e] = (mm < mlim) ? pv : 0.0f;
                    Ls += p[e];
                }
                unsigned w0 = (unsigned)bf16_rn(p[0]) | ((unsigned)bf16_rn(p[1]) << 16);
                unsigned w1 = (unsigned)bf16_rn(p[2]) | ((unsigned)bf16_rn(p[3]) << 16);
                int mbase = sub * 16 + g * 4;
                *reinterpret_cast<unsigned*>(&Pl[w][fr][mbase])     = w0;
                *reinterpret_cast<unsigned*>(&Pl[w][fr][mbase + 2]) = w1;
            }
            Ls += __shfl_xor(Ls, 16);
            Ls += __shfl_xor(Ls, 32);
            L[i] += Ls;
            // PV: O[d][n] += V[d][m] * P[n][m]
#pragma unroll
            for (int kc = 0; kc < 2; ++kc) {
                s8v pf = *reinterpret_cast<const s8v*>(&Pl[w][fr][kc * 32 + g * 8]);
                s8v v0 = *reinterpret_cast<const s8v*>(&Vs[fr][kc * 32 + g * 8]);
                s8v v1 = *reinterpret_cast<const s8v*>(&Vs[16 + fr][kc * 32 + g * 8]);
                Oa[i][0] = __builtin_amdgcn_mfma_f32_16x16x32_bf16(v0, pf, Oa[i][0], 0, 0, 0);
                Oa[i][1] = __builtin_amdgcn_mfma_f32_16x16x32_bf16(v1, pf, Oa[i][1], 0, 0, 0);
            }
        }
    }

    // ---- epilogue: normalize + hswish + store ----
#pragma unroll
    for (int i = 0; i < 4; ++i) {
        int tile = i * 4 + w;
        if (tile >= 13) continue;
        int n = tile * 16 + fr;
        if (n < 196) {
            float inv = 1.0f / L[i];
#pragma unroll
            for (int dt = 0; dt < 2; ++dt)
#pragma unroll
                for (int e = 0; e < 4; ++e) {
                    int d = dt * 16 + g * 4 + e;
                    float z = Oa[i][dt][e] * inv;
                    act[((size_t)b * 256 + h * 32 + d) * 196 + n] = hswish(z);
                }
        }
    }
}

// ---------------------------------------------------------------------------
extern "C" void kernel_launch(void* const* d_in, const int* in_sizes, int n_in,
                              void* d_out, int out_size, void* d_ws, size_t ws_size,
                              hipStream_t stream) {
    const float* x      = (const float*)d_in[0];
    const float* kv_w   = (const float*)d_in[1];
    const float* kv_g   = (const float*)d_in[2];
    const float* kv_b   = (const float*)d_in[3];
    const float* kv_m   = (const float*)d_in[4];
    const float* kv_v   = (const float*)d_in[5];
    const float* q_w    = (const float*)d_in[6];
    const float* q_g    = (const float*)d_in[7];
    const float* q_b    = (const float*)d_in[8];
    const float* q_m    = (const float*)d_in[9];
    const float* q_v    = (const float*)d_in[10];
    const float* proj_w = (const float*)d_in[11];
    const float* proj_g = (const float*)d_in[12];
    const float* proj_b = (const float*)d_in[13];
    const float* proj_m = (const float*)d_in[14];
    const float* proj_v = (const float*)d_in[15];
    const float* ab     = (const float*)d_in[16];
    const int*   idxs   = (const int*)d_in[17];
    float* out = (float*)d_out;

    int n_off = in_sizes[16] / 8;

    // workspace layout
    const size_t KV_ELEMS   = (size_t)64 * 384 * 784;        // floats
    const size_t Q_ELEMS    = (size_t)64 * 128 * 196;        // floats
    const size_t BIAS_SHORT = (size_t)8 * 784 * 208;         // ushorts
    float* kvbuf = (float*)d_ws;
    float* qbuf  = kvbuf + KV_ELEMS;
    unsigned short* biasB = (unsigned short*)(qbuf + Q_ELEMS);
    float* actb  = (float*)(biasB + BIAS_SHORT);

    // 1. bias gather (bf16, padded to 208)
    {
        dim3 g(25, 7);
        bias_kernel<<<g, 256, 0, stream>>>(ab, idxs, biasB, n_off);
    }
    // 2. kv : O=384, N=784
    {
        dim3 g(13, 6, 64);
        convbn_mfma<false><<<g, 256, 0, stream>>>(x, kv_w, kv_g, kv_b, kv_m, kv_v,
                                                  kvbuf, 384, 784, 256 * 784, 784);
    }
    // 3. q : O=128, N=196 (strided x)
    {
        dim3 g(4, 2, 64);
        convbn_mfma<true><<<g, 256, 0, stream>>>(x, q_w, q_g, q_b, q_m, q_v,
                                                 qbuf, 128, 196, 256 * 784, 784);
    }
    // 4. MFMA flash attention -> act
    {
        attn_mfma<<<512, 256, 0, stream>>>(kvbuf, qbuf, biasB, actb);
    }
    // 5. proj : O=512, N=196
    {
        dim3 g(4, 8, 64);
        convbn_mfma<false><<<g, 256, 0, stream>>>(actb, proj_w, proj_g, proj_b, proj_m, proj_v,
                                                  out, 512, 196, 256 * 196, 196);
    }
}